// Round 16
// baseline (232.738 us; speedup 1.0000x reference)
//
#include <hip/hip_runtime.h>
#include <stdint.h>

#define HID 1024
#define NEXP 8
#define NTOK 16384
#define CAP 8192

typedef __attribute__((ext_vector_type(8))) __bf16 bf16x8;
typedef __attribute__((ext_vector_type(8))) short short8;
typedef __attribute__((ext_vector_type(4))) float f32x4;

__device__ __forceinline__ ushort f2bf(float f) {
  uint32_t u = __builtin_bit_cast(uint32_t, f);
  u += 0x7FFF + ((u >> 16) & 1);          // round-to-nearest-even
  return (ushort)(u >> 16);
}
__device__ __forceinline__ float bf2f(ushort u) {
  return __builtin_bit_cast(float, (uint32_t)u << 16);
}

__device__ __forceinline__ void gl16(const void* g, void* l) {
  __builtin_amdgcn_global_load_lds((__attribute__((address_space(1))) void*)(g),
                                   (__attribute__((address_space(3))) void*)(l),
                                   16, 0, 0);
}

__global__ void zero_kernel(int* counts) {
  if (threadIdx.x < 16) counts[threadIdx.x] = 0;
}

// ---------------- fused gate + weight conversions (concurrent BW streams) ----------------
__global__ __launch_bounds__(256) void gate_cvt_kernel(
    const float* __restrict__ tokens, const float* __restrict__ gate_w,
    const float* __restrict__ expert_w, const float* __restrict__ combine_w,
    ushort* __restrict__ Xb, ushort* __restrict__ Wxb, ushort* __restrict__ Wcb,
    uint32_t* __restrict__ tinfo, float2* __restrict__ tw) {
  const int b = blockIdx.x;
  if (b >= 2048) {
    const float* src; ushort* dst; int n4, i, stride;
    if (b < 3072) { src = expert_w;  dst = Wxb; n4 = NEXP * HID * HID / 4;
                    i = (b - 2048) * 256 + threadIdx.x; stride = 1024 * 256; }
    else          { src = combine_w; dst = Wcb; n4 = HID * HID / 4;
                    i = (b - 3072) * 256 + threadIdx.x; stride = 256 * 256; }
    for (; i < n4; i += stride) {
      float4 v = reinterpret_cast<const float4*>(src)[i];
      reinterpret_cast<ushort4*>(dst)[i] =
          make_ushort4(f2bf(v.x), f2bf(v.y), f2bf(v.z), f2bf(v.w));
    }
    return;
  }
  const int lane = threadIdx.x & 63;
  const int wave = threadIdx.x >> 6;
  float4 rg[NEXP][4];
#pragma unroll
  for (int e = 0; e < NEXP; e++)
#pragma unroll
    for (int j = 0; j < 4; j++)
      rg[e][j] = reinterpret_cast<const float4*>(gate_w)[e * 256 + j * 64 + lane];

  const int gwid = b * 4 + wave;
  const int nw = 2048 * 4;
  for (int t = gwid; t < NTOK; t += nw) {
    const float4* xr = reinterpret_cast<const float4*>(tokens + (size_t)t * HID);
    float acc[NEXP];
#pragma unroll
    for (int e = 0; e < NEXP; e++) acc[e] = 0.f;
    ushort4 xs[4];
#pragma unroll
    for (int j = 0; j < 4; j++) {
      float4 x = xr[j * 64 + lane];
      xs[j] = make_ushort4(f2bf(x.x), f2bf(x.y), f2bf(x.z), f2bf(x.w));
#pragma unroll
      for (int e = 0; e < NEXP; e++) {
        acc[e] = fmaf(x.x, rg[e][j].x,
                 fmaf(x.y, rg[e][j].y,
                 fmaf(x.z, rg[e][j].z,
                 fmaf(x.w, rg[e][j].w, acc[e]))));
      }
    }
    ushort4* xo = reinterpret_cast<ushort4*>(Xb + (size_t)t * HID);
#pragma unroll
    for (int j = 0; j < 4; j++) xo[j * 64 + lane] = xs[j];
#pragma unroll
    for (int e = 0; e < NEXP; e++) {
#pragma unroll
      for (int s = 32; s > 0; s >>= 1) acc[e] += __shfl_xor(acc[e], s);
    }
    int i1 = 0;
#pragma unroll
    for (int e = 1; e < NEXP; e++) if (acc[e] > acc[i1]) i1 = e;
    int i2 = (i1 == 0) ? 1 : 0;
#pragma unroll
    for (int e = 0; e < NEXP; e++) if (e != i1 && acc[e] > acc[i2]) i2 = e;
    float m = acc[i1];
    float s = 0.f;
#pragma unroll
    for (int e = 0; e < NEXP; e++) s += __expf(acc[e] - m);
    float w1 = 1.f / s;
    float w2 = __expf(acc[i2] - m) / s;
    if (lane == 0) {
      tinfo[t] = (uint32_t)i1 | ((uint32_t)i2 << 8);
      tw[t] = make_float2(w1, w2);
    }
  }
}

// ---------------- scatter: block-aggregated list build ----------------
__global__ __launch_bounds__(256) void scatter_kernel(
    const uint32_t* __restrict__ tinfo, const float2* __restrict__ tw,
    int* __restrict__ list, float* __restrict__ listw, int* __restrict__ counts) {
  __shared__ int lhist[NEXP];
  __shared__ int gbase[NEXP];
  const int tid = threadIdx.x;
  if (tid < NEXP) lhist[tid] = 0;
  __syncthreads();
  const int t = blockIdx.x * 256 + tid;
  uint32_t info = tinfo[t];
  int i1 = info & 0xFF, i2 = (info >> 8) & 0xFF;
  float2 w = tw[t];
  int lr1 = atomicAdd(&lhist[i1], 1);
  int lr2 = atomicAdd(&lhist[i2], 1);
  __syncthreads();
  if (tid < NEXP) gbase[tid] = atomicAdd(&counts[tid], lhist[tid]);
  __syncthreads();
  int p1 = gbase[i1] + lr1;
  if (p1 < CAP) { list[i1 * CAP + p1] = t;           listw[i1 * CAP + p1] = w.x; }
  int p2 = gbase[i2] + lr2;
  if (p2 < CAP) { list[i2 * CAP + p2] = t | 0x10000; listw[i2 * CAP + p2] = w.y; }
}

// 4 A frags + 4 B frags (16-row stride = 512 ushorts) + 16 MFMA (64x64 wave tile)
#define LDFRAGS(AB, BB) \
    bf16x8 av0 = *(const bf16x8*)(AB);          bf16x8 av1 = *(const bf16x8*)((AB) + 512); \
    bf16x8 av2 = *(const bf16x8*)((AB) + 1024); bf16x8 av3 = *(const bf16x8*)((AB) + 1536); \
    bf16x8 bv0 = *(const bf16x8*)(BB);          bf16x8 bv1 = *(const bf16x8*)((BB) + 512); \
    bf16x8 bv2 = *(const bf16x8*)((BB) + 1024); bf16x8 bv3 = *(const bf16x8*)((BB) + 1536);
#define MF16 do { \
    acc[0][0] = __builtin_amdgcn_mfma_f32_16x16x32_bf16(av0, bv0, acc[0][0], 0, 0, 0); \
    acc[0][1] = __builtin_amdgcn_mfma_f32_16x16x32_bf16(av0, bv1, acc[0][1], 0, 0, 0); \
    acc[0][2] = __builtin_amdgcn_mfma_f32_16x16x32_bf16(av0, bv2, acc[0][2], 0, 0, 0); \
    acc[0][3] = __builtin_amdgcn_mfma_f32_16x16x32_bf16(av0, bv3, acc[0][3], 0, 0, 0); \
    acc[1][0] = __builtin_amdgcn_mfma_f32_16x16x32_bf16(av1, bv0, acc[1][0], 0, 0, 0); \
    acc[1][1] = __builtin_amdgcn_mfma_f32_16x16x32_bf16(av1, bv1, acc[1][1], 0, 0, 0); \
    acc[1][2] = __builtin_amdgcn_mfma_f32_16x16x32_bf16(av1, bv2, acc[1][2], 0, 0, 0); \
    acc[1][3] = __builtin_amdgcn_mfma_f32_16x16x32_bf16(av1, bv3, acc[1][3], 0, 0, 0); \
    acc[2][0] = __builtin_amdgcn_mfma_f32_16x16x32_bf16(av2, bv0, acc[2][0], 0, 0, 0); \
    acc[2][1] = __builtin_amdgcn_mfma_f32_16x16x32_bf16(av2, bv1, acc[2][1], 0, 0, 0); \
    acc[2][2] = __builtin_amdgcn_mfma_f32_16x16x32_bf16(av2, bv2, acc[2][2], 0, 0, 0); \
    acc[2][3] = __builtin_amdgcn_mfma_f32_16x16x32_bf16(av2, bv3, acc[2][3], 0, 0, 0); \
    acc[3][0] = __builtin_amdgcn_mfma_f32_16x16x32_bf16(av3, bv0, acc[3][0], 0, 0, 0); \
    acc[3][1] = __builtin_amdgcn_mfma_f32_16x16x32_bf16(av3, bv1, acc[3][1], 0, 0, 0); \
    acc[3][2] = __builtin_amdgcn_mfma_f32_16x16x32_bf16(av3, bv2, acc[3][2], 0, 0, 0); \
    acc[3][3] = __builtin_amdgcn_mfma_f32_16x16x32_bf16(av3, bv3, acc[3][3], 0, 0, 0); } while (0)

// ---------------- expert GEMM: 128x256x32, 8 waves, 2-buffer (48 KB -> 3 blocks/CU) ----------------
// Sound step: vmcnt(0) (only tile-T loads outstanding; drains them) -> barrier
// (publishes tile-T landed block-wide AND tile-(T-1) reads done) -> stage(T+1)
// into buf[(T-1)&1] (WAR-safe) -> read(T) (RAW-safe).
__global__ __launch_bounds__(512, 2) void egemm_kernel(
    const ushort* __restrict__ Ab, const ushort* __restrict__ Bb,
    const float* __restrict__ bias,
    const int* __restrict__ list, const float* __restrict__ listw,
    const int* __restrict__ counts, ushort* __restrict__ contrib) {
  __shared__ ushort As[2][128 * 32];   // 16 KB
  __shared__ ushort Bs[2][256 * 32];   // 32 KB
  const int tid = threadIdx.x, lane = tid & 63, wid = tid >> 6;
  const int p = blockIdx.x;
  const int ct = (p >> 3) & 3;
  const int gg = ((p >> 5) << 3) | (p & 7);   // 4 ct-blocks of (e,rt) share p%8 (XCD)
  const int e = gg >> 6, rt = gg & 63;
  int count = counts[e]; if (count > CAP) count = CAP;
  if (rt * 128 >= count) return;

  const int arow = tid >> 2;                       // 0..127
  const int g0 = tid & 3;
  const int swz8 = (g0 ^ ((arow >> 1) & 3)) * 8;   // pre-swizzled source granule
  int rA = rt * 128 + arow;
  int tokA = (rA < count) ? (list[e * CAP + rA] & 0xFFFF) : 0;
  const ushort* srcA = Ab + (size_t)tokA * HID + swz8;
  const ushort* Bbase = Bb + (size_t)e * HID * HID;
  const ushort* srcB0 = Bbase + (size_t)(ct * 256 + arow) * HID + swz8;
  const ushort* srcB1 = srcB0 + (size_t)128 * HID;

  f32x4 acc[4][4];
#pragma unroll
  for (int m = 0; m < 4; m++)
#pragma unroll
    for (int n = 0; n < 4; n++) acc[m][n] = (f32x4){0.f, 0.f, 0.f, 0.f};

  const int wm = wid >> 2, wn = wid & 3;           // 2 x 4 wave grid
  const int fr = lane & 15, fq = lane >> 4;
  const int sa = (fq ^ ((fr >> 1) & 3)) * 8;

  ushort* dA0 = &As[0][wid * 512]; ushort* dA1 = &As[1][wid * 512];
  ushort* dB0 = &Bs[0][wid * 512]; ushort* dB1 = &Bs[1][wid * 512];
  const ushort* aR0 = &As[0][(wm * 64 + fr) * 32 + sa];
  const ushort* aR1 = &As[1][(wm * 64 + fr) * 32 + sa];
  const ushort* bR0 = &Bs[0][(wn * 64 + fr) * 32 + sa];
  const ushort* bR1 = &Bs[1][(wn * 64 + fr) * 32 + sa];

#define ESTG(K0, J) do { \
    gl16(srcA + (K0), (J) ? dA1 : dA0); \
    gl16(srcB0 + (K0), (J) ? dB1 : dB0); \
    gl16(srcB1 + (K0), ((J) ? dB1 : dB0) + 4096); } while (0)
#define EKS(T) do { \
    asm volatile("s_waitcnt vmcnt(0)" ::: "memory"); \
    __builtin_amdgcn_s_barrier(); \
    asm volatile("" ::: "memory"); \
    if ((T) + 1 < 32) ESTG(((T) + 1) * 32, ((T) + 1) & 1); \
    LDFRAGS(((T) & 1) ? aR1 : aR0, ((T) & 1) ? bR1 : bR0); \
    MF16; } while (0)

  ESTG(0, 0);
  EKS(0);  EKS(1);  EKS(2);  EKS(3);  EKS(4);  EKS(5);  EKS(6);  EKS(7);
  EKS(8);  EKS(9);  EKS(10); EKS(11); EKS(12); EKS(13); EKS(14); EKS(15);
  EKS(16); EKS(17); EKS(18); EKS(19); EKS(20); EKS(21); EKS(22); EKS(23);
  EKS(24); EKS(25); EKS(26); EKS(27); EKS(28); EKS(29); EKS(30); EKS(31);
#undef ESTG
#undef EKS

  // epilogue: batched meta loads + rcp-based sigmoid (wave tile 64x64)
  const int colb = ct * 256 + wn * 64 + fr;
  float bc[4];
#pragma unroll
  for (int n = 0; n < 4; n++) bc[n] = bias[e * HID + colb + n * 16];
  const int rb = rt * 128 + wm * 64 + fq * 4;
  int ents[16]; float ws[16];
#pragma unroll
  for (int m = 0; m < 4; m++)
#pragma unroll
    for (int rr = 0; rr < 4; rr++) {
      int r = rb + m * 16 + rr;
      bool v = (r < count);
      ents[m * 4 + rr] = v ? list[e * CAP + r] : -1;
      ws[m * 4 + rr]   = v ? listw[e * CAP + r] : 0.f;
    }
#pragma unroll
  for (int m = 0; m < 4; m++) {
#pragma unroll
    for (int rr = 0; rr < 4; rr++) {
      int ent = ents[m * 4 + rr];
      if (ent >= 0) {
        int tok = ent & 0xFFFF;
        int slot = (ent >> 16) & 1;
        float wgt = ws[m * 4 + rr];
        ushort* dst = contrib + ((size_t)slot * NTOK + tok) * HID;
#pragma unroll
        for (int n = 0; n < 4; n++) {
          float v = acc[m][n][rr] + bc[n];
          float sv = v * __builtin_amdgcn_rcpf(1.0f + __expf(-v));
          dst[colb + n * 16] = f2bf(sv * wgt);
        }
      }
    }
  }
}

// ---------------- combine GEMM: 128x256x32, 8 waves, 3-buffer A+B, fused mix ----------------
// (r15, passing) A = c0+c1 via reg-load -> bfadd -> swizzled ds_write; explicit
// fenced regions; end-of-step lgkm(0) + vmcnt(4) (drains prev region) + barrier.
__global__ __launch_bounds__(512, 2) void cgemm_kernel(
    const ushort* __restrict__ Cb, const ushort* __restrict__ Bb,
    float* __restrict__ outp) {
  __shared__ ushort As[3][128 * 32];   // 24 KB
  __shared__ ushort Bs[3][256 * 32];   // 48 KB
  const int tid = threadIdx.x, lane = tid & 63, wid = tid >> 6;
  const int p = blockIdx.x;                 // 512 blocks
  const int ct = (p >> 3) & 3;
  const int rt = ((p >> 5) << 3) | (p & 7); // rt < 128

  const int arow = tid >> 2;
  const int g0 = tid & 3;
  const int nat8 = g0 * 8;
  const int swz8 = (g0 ^ ((arow >> 1) & 3)) * 8;

  const ushort* srcB0 = Bb + (size_t)(ct * 256 + arow) * HID + swz8;
  const ushort* srcB1 = srcB0 + (size_t)128 * HID;
  const ushort* sAc0 = Cb + (size_t)(rt * 128 + arow) * HID + nat8;
  const ushort* sAc1 = sAc0 + (size_t)NTOK * HID;

  f32x4 acc[4][4];
#pragma unroll
  for (int m = 0; m < 4; m++)
#pragma unroll
    for (int n = 0; n < 4; n++) acc[m][n] = (f32x4){0.f, 0.f, 0.f, 0.f};

  const int wm = wid >> 2, wn = wid & 3;
  const int fr = lane & 15, fq = lane >> 4;
  const int sa = (fq ^ ((fr >> 1) & 3)) * 8;

  ushort* dB0 = &Bs[0][wid * 512]; ushort* dB1 = &Bs[1][wid * 512]; ushort* dB2 = &Bs[2][wid * 512];
  ushort* wA0 = &As[0][arow * 32 + swz8];
  ushort* wA1 = &As[1][arow * 32 + swz8];
  ushort* wA2 = &As[2][arow * 32 + swz8];
  const ushort* aR0 = &As[0][(wm * 64 + fr) * 32 + sa];
  const ushort* aR1 = &As[1][(wm * 64 + fr) * 32 + sa];
  const ushort* aR2 = &As[2][(wm * 64 + fr) * 32 + sa];
  const ushort* bR0 = &Bs[0][(wn * 64 + fr) * 32 + sa];
  const ushort* bR1 = &Bs[1][(wn * 64 + fr) * 32 + sa];
  const ushort* bR2 = &Bs[2][(wn * 64 + fr) * 32 + sa];

  auto bfadd8 = [](short8 a, short8 b) {
    union { short8 s; uint32_t u[4]; } o;
#pragma unroll
    for (int j = 0; j < 4; j++) {
      float x0 = bf2f((ushort)a[2 * j])     + bf2f((ushort)b[2 * j]);
      float x1 = bf2f((ushort)a[2 * j + 1]) + bf2f((ushort)b[2 * j + 1]);
      uint32_t pk;
      asm("v_cvt_pk_bf16_f32 %0, %1, %2" : "=v"(pk) : "v"(x0), "v"(x1));
      o.u[j] = pk;
    }
    return o.s;
  };

#define CDB(J) ((J) == 0 ? dB0 : (J) == 1 ? dB1 : dB2)
#define CWA(J) ((J) == 0 ? wA0 : (J) == 1 ? wA1 : wA2)
#define CRA(J) ((J) == 0 ? aR0 : (J) == 1 ? aR1 : aR2)
#define CRB(J) ((J) == 0 ? bR0 : (J) == 1 ? bR1 : bR2)
#define CSTB(K0, J) do { \
    gl16(srcB0 + (K0), CDB(J)); \
    gl16(srcB1 + (K0), CDB(J) + 4096); } while (0)

  short8 na0, nb0, na1, nb1;   // reg set (t&1) holds A-tile t
  CSTB(0, 0);
  na0 = *(const short8*)(sAc0); nb0 = *(const short8*)(sAc1);
  asm volatile("" ::: "memory");
  CSTB(32, 1);
  na1 = *(const short8*)(sAc0 + 32); nb1 = *(const short8*)(sAc1 + 32);
  asm volatile("s_waitcnt vmcnt(4)" ::: "memory");   // drains P1: B(0) in LDS, set0 regs ready
  *(short8*)wA0 = bfadd8(na0, nb0);                   // A(0) -> bufA[0]
  asm volatile("s_waitcnt lgkmcnt(0)" ::: "memory");
  __builtin_amdgcn_s_barrier();

#define CKS(T) do { \
    if ((T) + 2 < 32) CSTB(((T) + 2) * 32, ((T) + 2) % 3); \
    { \
      short8 w = (((T) + 1) & 1) ? bfadd8(na1, nb1) : bfadd8(na0, nb0); \
      *(short8*)(CWA(((T) + 1) % 3)) = w; \
    } \
    if ((T) + 2 < 32) { \
      if (((T) + 2) & 1) { na1 = *(const short8*)(sAc0 + ((T) + 2) * 32); \
                           nb1 = *(const short8*)(sAc1 + ((T) + 2) * 32); } \
      else               { na0 = *(const short8*)(sAc0 + ((T) + 2) * 32); \
                           nb0 = *(const short8*)(sAc1 + ((T) + 2) * 32); } \
    } \
    LDFRAGS(CRA((T) % 3), CRB((T) % 3)); \
    MF16; \
    asm volatile("s_waitcnt lgkmcnt(0)" ::: "memory"); \
    if ((T) < 30)       asm volatile("s_waitcnt vmcnt(4)" ::: "memory"); \
    else if ((T) == 30) asm volatile("s_waitcnt vmcnt(0)" ::: "memory"); \
    if ((T) < 31) __builtin_amdgcn_s_barrier(); \
  } while (0)

  CKS(0);  CKS(1);  CKS(2);  CKS(3);  CKS(4);  CKS(5);  CKS(6);  CKS(7);
  CKS(8);  CKS(9);  CKS(10); CKS(11); CKS(12); CKS(13); CKS(14); CKS(15);
  CKS(16); CKS(17); CKS(18); CKS(19); CKS(20); CKS(21); CKS(22); CKS(23);
  CKS(24); CKS(25); CKS(26); CKS(27); CKS(28); CKS(29); CKS(30); CKS(31);
#undef CKS
#undef CSTB
#undef CDB
#undef CWA
#undef CRA
#undef CRB

  const int colb = ct * 256 + wn * 64 + fr;
#pragma unroll
  for (int m = 0; m < 4; m++)
#pragma unroll
    for (int rr = 0; rr < 4; rr++) {
      int r = rt * 128 + wm * 64 + m * 16 + fq * 4 + rr;
      float* dst = outp + (size_t)r * HID;
#pragma unroll
      for (int n = 0; n < 4; n++) dst[colb + n * 16] = acc[m][n][rr];
    }
}

extern "C" void kernel_launch(void* const* d_in, const int* in_sizes, int n_in,
                              void* d_out, int out_size, void* d_ws, size_t ws_size,
                              hipStream_t stream) {
  const float* tokens    = (const float*)d_in[0];
  const float* gate_w    = (const float*)d_in[1];
  const float* expert_w  = (const float*)d_in[2];
  const float* expert_b  = (const float*)d_in[3];
  const float* combine_w = (const float*)d_in[4];
  float* outp = (float*)d_out;

  char* p = (char*)d_ws;
  ushort* Xb  = (ushort*)p; p += (size_t)NTOK * HID * 2;        // 33.5 MB
  ushort* Wxb = (ushort*)p; p += (size_t)NEXP * HID * HID * 2;  // 16.8 MB
  ushort* Wcb = (ushort*)p; p += (size_t)HID * HID * 2;         //  2.1 MB
  ushort* ctb = (ushort*)p; p += (size_t)2 * NTOK * HID * 2;    // 67.1 MB
  int*   list = (int*)p;    p += (size_t)NEXP * CAP * 4;
  float* lsw  = (float*)p;  p += (size_t)NEXP * CAP * 4;
  int*   cnts = (int*)p;    p += 256;
  uint32_t* tinfo = (uint32_t*)p; p += (size_t)NTOK * 4;
  float2*   twp   = (float2*)p;   p += (size_t)NTOK * 8;

  zero_kernel<<<1, 64, 0, stream>>>(cnts);
  gate_cvt_kernel<<<3328, 256, 0, stream>>>(tokens, gate_w, expert_w, combine_w,
                                            Xb, Wxb, Wcb, tinfo, twp);
  scatter_kernel<<<64, 256, 0, stream>>>(tinfo, twp, list, lsw, cnts);
  egemm_kernel<<<2048, 512, 0, stream>>>(Xb, Wxb, expert_b, list, lsw, cnts, ctb);
  cgemm_kernel<<<512, 512, 0, stream>>>(ctb, Wcb, outp);
}

// Round 17
// 191.780 us; speedup vs baseline: 1.2136x; 1.2136x over previous
//
#include <hip/hip_runtime.h>
#include <stdint.h>

#define HID 1024
#define NEXP 8
#define NTOK 16384
#define CAP 8192

typedef __attribute__((ext_vector_type(8))) __bf16 bf16x8;
typedef __attribute__((ext_vector_type(8))) short short8;
typedef __attribute__((ext_vector_type(4))) float f32x4;

__device__ __forceinline__ ushort f2bf(float f) {
  uint32_t u = __builtin_bit_cast(uint32_t, f);
  u += 0x7FFF + ((u >> 16) & 1);          // round-to-nearest-even
  return (ushort)(u >> 16);
}
__device__ __forceinline__ float bf2f(ushort u) {
  return __builtin_bit_cast(float, (uint32_t)u << 16);
}

__device__ __forceinline__ void gl16(const void* g, void* l) {
  __builtin_amdgcn_global_load_lds((__attribute__((address_space(1))) void*)(g),
                                   (__attribute__((address_space(3))) void*)(l),
                                   16, 0, 0);
}

__global__ void zero_kernel(int* counts) {
  if (threadIdx.x < 16) counts[threadIdx.x] = 0;
}

// ---------------- fused gate + weight conversions (concurrent BW streams) ----------------
__global__ __launch_bounds__(256) void gate_cvt_kernel(
    const float* __restrict__ tokens, const float* __restrict__ gate_w,
    const float* __restrict__ expert_w, const float* __restrict__ combine_w,
    ushort* __restrict__ Xb, ushort* __restrict__ Wxb, ushort* __restrict__ Wcb,
    uint32_t* __restrict__ tinfo, float2* __restrict__ tw) {
  const int b = blockIdx.x;
  if (b >= 2048) {
    const float* src; ushort* dst; int n4, i, stride;
    if (b < 3072) { src = expert_w;  dst = Wxb; n4 = NEXP * HID * HID / 4;
                    i = (b - 2048) * 256 + threadIdx.x; stride = 1024 * 256; }
    else          { src = combine_w; dst = Wcb; n4 = HID * HID / 4;
                    i = (b - 3072) * 256 + threadIdx.x; stride = 256 * 256; }
    for (; i < n4; i += stride) {
      float4 v = reinterpret_cast<const float4*>(src)[i];
      reinterpret_cast<ushort4*>(dst)[i] =
          make_ushort4(f2bf(v.x), f2bf(v.y), f2bf(v.z), f2bf(v.w));
    }
    return;
  }
  const int lane = threadIdx.x & 63;
  const int wave = threadIdx.x >> 6;
  float4 rg[NEXP][4];
#pragma unroll
  for (int e = 0; e < NEXP; e++)
#pragma unroll
    for (int j = 0; j < 4; j++)
      rg[e][j] = reinterpret_cast<const float4*>(gate_w)[e * 256 + j * 64 + lane];

  const int gwid = b * 4 + wave;
  const int nw = 2048 * 4;
  for (int t = gwid; t < NTOK; t += nw) {
    const float4* xr = reinterpret_cast<const float4*>(tokens + (size_t)t * HID);
    float acc[NEXP];
#pragma unroll
    for (int e = 0; e < NEXP; e++) acc[e] = 0.f;
    ushort4 xs[4];
#pragma unroll
    for (int j = 0; j < 4; j++) {
      float4 x = xr[j * 64 + lane];
      xs[j] = make_ushort4(f2bf(x.x), f2bf(x.y), f2bf(x.z), f2bf(x.w));
#pragma unroll
      for (int e = 0; e < NEXP; e++) {
        acc[e] = fmaf(x.x, rg[e][j].x,
                 fmaf(x.y, rg[e][j].y,
                 fmaf(x.z, rg[e][j].z,
                 fmaf(x.w, rg[e][j].w, acc[e]))));
      }
    }
    ushort4* xo = reinterpret_cast<ushort4*>(Xb + (size_t)t * HID);
#pragma unroll
    for (int j = 0; j < 4; j++) xo[j * 64 + lane] = xs[j];
#pragma unroll
    for (int e = 0; e < NEXP; e++) {
#pragma unroll
      for (int s = 32; s > 0; s >>= 1) acc[e] += __shfl_xor(acc[e], s);
    }
    int i1 = 0;
#pragma unroll
    for (int e = 1; e < NEXP; e++) if (acc[e] > acc[i1]) i1 = e;
    int i2 = (i1 == 0) ? 1 : 0;
#pragma unroll
    for (int e = 0; e < NEXP; e++) if (e != i1 && acc[e] > acc[i2]) i2 = e;
    float m = acc[i1];
    float s = 0.f;
#pragma unroll
    for (int e = 0; e < NEXP; e++) s += __expf(acc[e] - m);
    float w1 = 1.f / s;
    float w2 = __expf(acc[i2] - m) / s;
    if (lane == 0) {
      tinfo[t] = (uint32_t)i1 | ((uint32_t)i2 << 8);
      tw[t] = make_float2(w1, w2);
    }
  }
}

// ---------------- scatter: block-aggregated list build ----------------
__global__ __launch_bounds__(256) void scatter_kernel(
    const uint32_t* __restrict__ tinfo, const float2* __restrict__ tw,
    int* __restrict__ list, float* __restrict__ listw, int* __restrict__ counts) {
  __shared__ int lhist[NEXP];
  __shared__ int gbase[NEXP];
  const int tid = threadIdx.x;
  if (tid < NEXP) lhist[tid] = 0;
  __syncthreads();
  const int t = blockIdx.x * 256 + tid;
  uint32_t info = tinfo[t];
  int i1 = info & 0xFF, i2 = (info >> 8) & 0xFF;
  float2 w = tw[t];
  int lr1 = atomicAdd(&lhist[i1], 1);
  int lr2 = atomicAdd(&lhist[i2], 1);
  __syncthreads();
  if (tid < NEXP) gbase[tid] = atomicAdd(&counts[tid], lhist[tid]);
  __syncthreads();
  int p1 = gbase[i1] + lr1;
  if (p1 < CAP) { list[i1 * CAP + p1] = t;           listw[i1 * CAP + p1] = w.x; }
  int p2 = gbase[i2] + lr2;
  if (p2 < CAP) { list[i2 * CAP + p2] = t | 0x10000; listw[i2 * CAP + p2] = w.y; }
}

// 4 A frags + 4 B frags (16-row stride = 512 ushorts) + 16 MFMA (64x64 wave tile)
#define LDFRAGS(AB, BB) \
    bf16x8 av0 = *(const bf16x8*)(AB);          bf16x8 av1 = *(const bf16x8*)((AB) + 512); \
    bf16x8 av2 = *(const bf16x8*)((AB) + 1024); bf16x8 av3 = *(const bf16x8*)((AB) + 1536); \
    bf16x8 bv0 = *(const bf16x8*)(BB);          bf16x8 bv1 = *(const bf16x8*)((BB) + 512); \
    bf16x8 bv2 = *(const bf16x8*)((BB) + 1024); bf16x8 bv3 = *(const bf16x8*)((BB) + 1536);
#define MF16 do { \
    acc[0][0] = __builtin_amdgcn_mfma_f32_16x16x32_bf16(av0, bv0, acc[0][0], 0, 0, 0); \
    acc[0][1] = __builtin_amdgcn_mfma_f32_16x16x32_bf16(av0, bv1, acc[0][1], 0, 0, 0); \
    acc[0][2] = __builtin_amdgcn_mfma_f32_16x16x32_bf16(av0, bv2, acc[0][2], 0, 0, 0); \
    acc[0][3] = __builtin_amdgcn_mfma_f32_16x16x32_bf16(av0, bv3, acc[0][3], 0, 0, 0); \
    acc[1][0] = __builtin_amdgcn_mfma_f32_16x16x32_bf16(av1, bv0, acc[1][0], 0, 0, 0); \
    acc[1][1] = __builtin_amdgcn_mfma_f32_16x16x32_bf16(av1, bv1, acc[1][1], 0, 0, 0); \
    acc[1][2] = __builtin_amdgcn_mfma_f32_16x16x32_bf16(av1, bv2, acc[1][2], 0, 0, 0); \
    acc[1][3] = __builtin_amdgcn_mfma_f32_16x16x32_bf16(av1, bv3, acc[1][3], 0, 0, 0); \
    acc[2][0] = __builtin_amdgcn_mfma_f32_16x16x32_bf16(av2, bv0, acc[2][0], 0, 0, 0); \
    acc[2][1] = __builtin_amdgcn_mfma_f32_16x16x32_bf16(av2, bv1, acc[2][1], 0, 0, 0); \
    acc[2][2] = __builtin_amdgcn_mfma_f32_16x16x32_bf16(av2, bv2, acc[2][2], 0, 0, 0); \
    acc[2][3] = __builtin_amdgcn_mfma_f32_16x16x32_bf16(av2, bv3, acc[2][3], 0, 0, 0); \
    acc[3][0] = __builtin_amdgcn_mfma_f32_16x16x32_bf16(av3, bv0, acc[3][0], 0, 0, 0); \
    acc[3][1] = __builtin_amdgcn_mfma_f32_16x16x32_bf16(av3, bv1, acc[3][1], 0, 0, 0); \
    acc[3][2] = __builtin_amdgcn_mfma_f32_16x16x32_bf16(av3, bv2, acc[3][2], 0, 0, 0); \
    acc[3][3] = __builtin_amdgcn_mfma_f32_16x16x32_bf16(av3, bv3, acc[3][3], 0, 0, 0); } while (0)

// ---------------- expert GEMM: 128x256x32, 8 waves (16 waves/CU), 3-buffer ----------------
// Sound step: vmcnt(3) -> barrier -> stage(T+2) -> read(T).  (r14/r15, passing)
__global__ __launch_bounds__(512, 2) void egemm_kernel(
    const ushort* __restrict__ Ab, const ushort* __restrict__ Bb,
    const float* __restrict__ bias,
    const int* __restrict__ list, const float* __restrict__ listw,
    const int* __restrict__ counts, ushort* __restrict__ contrib) {
  __shared__ ushort As[3][128 * 32];   // 24 KB
  __shared__ ushort Bs[3][256 * 32];   // 48 KB
  const int tid = threadIdx.x, lane = tid & 63, wid = tid >> 6;
  const int p = blockIdx.x;
  const int ct = (p >> 3) & 3;
  const int gg = ((p >> 5) << 3) | (p & 7);   // 4 ct-blocks of (e,rt) share p%8 (XCD)
  const int e = gg >> 6, rt = gg & 63;
  int count = counts[e]; if (count > CAP) count = CAP;
  if (rt * 128 >= count) return;

  const int arow = tid >> 2;                       // 0..127
  const int g0 = tid & 3;
  const int swz8 = (g0 ^ ((arow >> 1) & 3)) * 8;   // pre-swizzled source granule
  int rA = rt * 128 + arow;
  int tokA = (rA < count) ? (list[e * CAP + rA] & 0xFFFF) : 0;
  const ushort* srcA = Ab + (size_t)tokA * HID + swz8;
  const ushort* Bbase = Bb + (size_t)e * HID * HID;
  const ushort* srcB0 = Bbase + (size_t)(ct * 256 + arow) * HID + swz8;
  const ushort* srcB1 = srcB0 + (size_t)128 * HID;

  f32x4 acc[4][4];
#pragma unroll
  for (int m = 0; m < 4; m++)
#pragma unroll
    for (int n = 0; n < 4; n++) acc[m][n] = (f32x4){0.f, 0.f, 0.f, 0.f};

  const int wm = wid >> 2, wn = wid & 3;           // 2 x 4 wave grid
  const int fr = lane & 15, fq = lane >> 4;
  const int sa = (fq ^ ((fr >> 1) & 3)) * 8;

  ushort* dA0 = &As[0][wid * 512]; ushort* dA1 = &As[1][wid * 512]; ushort* dA2 = &As[2][wid * 512];
  ushort* dB0 = &Bs[0][wid * 512]; ushort* dB1 = &Bs[1][wid * 512]; ushort* dB2 = &Bs[2][wid * 512];
  const ushort* aR0 = &As[0][(wm * 64 + fr) * 32 + sa];
  const ushort* aR1 = &As[1][(wm * 64 + fr) * 32 + sa];
  const ushort* aR2 = &As[2][(wm * 64 + fr) * 32 + sa];
  const ushort* bR0 = &Bs[0][(wn * 64 + fr) * 32 + sa];
  const ushort* bR1 = &Bs[1][(wn * 64 + fr) * 32 + sa];
  const ushort* bR2 = &Bs[2][(wn * 64 + fr) * 32 + sa];

#define EDA(J) ((J) == 0 ? dA0 : (J) == 1 ? dA1 : dA2)
#define EDB(J) ((J) == 0 ? dB0 : (J) == 1 ? dB1 : dB2)
#define ERA(J) ((J) == 0 ? aR0 : (J) == 1 ? aR1 : aR2)
#define ERB(J) ((J) == 0 ? bR0 : (J) == 1 ? bR1 : bR2)
#define ESTG(K0, J) do { \
    gl16(srcA + (K0), EDA(J)); \
    gl16(srcB0 + (K0), EDB(J)); gl16(srcB1 + (K0), EDB(J) + 4096); } while (0)
#define EKS(T) do { \
    if ((T) < 31) asm volatile("s_waitcnt vmcnt(3)" ::: "memory"); \
    else          asm volatile("s_waitcnt vmcnt(0)" ::: "memory"); \
    __builtin_amdgcn_s_barrier(); \
    asm volatile("" ::: "memory"); \
    if ((T) + 2 < 32) ESTG(((T) + 2) * 32, ((T) + 2) % 3); \
    LDFRAGS(ERA((T) % 3), ERB((T) % 3)); \
    MF16; } while (0)

  ESTG(0, 0); ESTG(32, 1);
  EKS(0);  EKS(1);  EKS(2);  EKS(3);  EKS(4);  EKS(5);  EKS(6);  EKS(7);
  EKS(8);  EKS(9);  EKS(10); EKS(11); EKS(12); EKS(13); EKS(14); EKS(15);
  EKS(16); EKS(17); EKS(18); EKS(19); EKS(20); EKS(21); EKS(22); EKS(23);
  EKS(24); EKS(25); EKS(26); EKS(27); EKS(28); EKS(29); EKS(30); EKS(31);
#undef ESTG
#undef EKS
#undef EDA
#undef EDB
#undef ERA
#undef ERB

  // epilogue: batched meta loads + rcp-based sigmoid (wave tile 64x64)
  const int colb = ct * 256 + wn * 64 + fr;
  float bc[4];
#pragma unroll
  for (int n = 0; n < 4; n++) bc[n] = bias[e * HID + colb + n * 16];
  const int rb = rt * 128 + wm * 64 + fq * 4;
  int ents[16]; float ws[16];
#pragma unroll
  for (int m = 0; m < 4; m++)
#pragma unroll
    for (int rr = 0; rr < 4; rr++) {
      int r = rb + m * 16 + rr;
      bool v = (r < count);
      ents[m * 4 + rr] = v ? list[e * CAP + r] : -1;
      ws[m * 4 + rr]   = v ? listw[e * CAP + r] : 0.f;
    }
#pragma unroll
  for (int m = 0; m < 4; m++) {
#pragma unroll
    for (int rr = 0; rr < 4; rr++) {
      int ent = ents[m * 4 + rr];
      if (ent >= 0) {
        int tok = ent & 0xFFFF;
        int slot = (ent >> 16) & 1;
        float wgt = ws[m * 4 + rr];
        ushort* dst = contrib + ((size_t)slot * NTOK + tok) * HID;
#pragma unroll
        for (int n = 0; n < 4; n++) {
          float v = acc[m][n][rr] + bc[n];
          float sv = v * __builtin_amdgcn_rcpf(1.0f + __expf(-v));
          dst[colb + n * 16] = f2bf(sv * wgt);
        }
      }
    }
  }
}

// ---------------- combine GEMM: 128x256x32, 8 waves, 3-buffer A+B, fused mix ----------------
// (r15, passing) A = c0+c1 via reg-load -> bfadd -> swizzled ds_write; explicit
// fenced regions; end-of-step lgkm(0) + vmcnt(4) (drains prev region) + barrier.
__global__ __launch_bounds__(512, 2) void cgemm_kernel(
    const ushort* __restrict__ Cb, const ushort* __restrict__ Bb,
    float* __restrict__ outp) {
  __shared__ ushort As[3][128 * 32];   // 24 KB
  __shared__ ushort Bs[3][256 * 32];   // 48 KB
  const int tid = threadIdx.x, lane = tid & 63, wid = tid >> 6;
  const int p = blockIdx.x;                 // 512 blocks
  const int ct = (p >> 3) & 3;
  const int rt = ((p >> 5) << 3) | (p & 7); // rt < 128

  const int arow = tid >> 2;
  const int g0 = tid & 3;
  const int nat8 = g0 * 8;
  const int swz8 = (g0 ^ ((arow >> 1) & 3)) * 8;

  const ushort* srcB0 = Bb + (size_t)(ct * 256 + arow) * HID + swz8;
  const ushort* srcB1 = srcB0 + (size_t)128 * HID;
  const ushort* sAc0 = Cb + (size_t)(rt * 128 + arow) * HID + nat8;
  const ushort* sAc1 = sAc0 + (size_t)NTOK * HID;

  f32x4 acc[4][4];
#pragma unroll
  for (int m = 0; m < 4; m++)
#pragma unroll
    for (int n = 0; n < 4; n++) acc[m][n] = (f32x4){0.f, 0.f, 0.f, 0.f};

  const int wm = wid >> 2, wn = wid & 3;
  const int fr = lane & 15, fq = lane >> 4;
  const int sa = (fq ^ ((fr >> 1) & 3)) * 8;

  ushort* dB0 = &Bs[0][wid * 512]; ushort* dB1 = &Bs[1][wid * 512]; ushort* dB2 = &Bs[2][wid * 512];
  ushort* wA0 = &As[0][arow * 32 + swz8];
  ushort* wA1 = &As[1][arow * 32 + swz8];
  ushort* wA2 = &As[2][arow * 32 + swz8];
  const ushort* aR0 = &As[0][(wm * 64 + fr) * 32 + sa];
  const ushort* aR1 = &As[1][(wm * 64 + fr) * 32 + sa];
  const ushort* aR2 = &As[2][(wm * 64 + fr) * 32 + sa];
  const ushort* bR0 = &Bs[0][(wn * 64 + fr) * 32 + sa];
  const ushort* bR1 = &Bs[1][(wn * 64 + fr) * 32 + sa];
  const ushort* bR2 = &Bs[2][(wn * 64 + fr) * 32 + sa];

  auto bfadd8 = [](short8 a, short8 b) {
    union { short8 s; uint32_t u[4]; } o;
#pragma unroll
    for (int j = 0; j < 4; j++) {
      float x0 = bf2f((ushort)a[2 * j])     + bf2f((ushort)b[2 * j]);
      float x1 = bf2f((ushort)a[2 * j + 1]) + bf2f((ushort)b[2 * j + 1]);
      uint32_t pk;
      asm("v_cvt_pk_bf16_f32 %0, %1, %2" : "=v"(pk) : "v"(x0), "v"(x1));
      o.u[j] = pk;
    }
    return o.s;
  };

#define CDB(J) ((J) == 0 ? dB0 : (J) == 1 ? dB1 : dB2)
#define CWA(J) ((J) == 0 ? wA0 : (J) == 1 ? wA1 : wA2)
#define CRA(J) ((J) == 0 ? aR0 : (J) == 1 ? aR1 : aR2)
#define CRB(J) ((J) == 0 ? bR0 : (J) == 1 ? bR1 : bR2)
#define CSTB(K0, J) do { \
    gl16(srcB0 + (K0), CDB(J)); \
    gl16(srcB1 + (K0), CDB(J) + 4096); } while (0)

  short8 na0, nb0, na1, nb1;   // reg set (t&1) holds A-tile t
  CSTB(0, 0);
  na0 = *(const short8*)(sAc0); nb0 = *(const short8*)(sAc1);
  asm volatile("" ::: "memory");
  CSTB(32, 1);
  na1 = *(const short8*)(sAc0 + 32); nb1 = *(const short8*)(sAc1 + 32);
  asm volatile("s_waitcnt vmcnt(4)" ::: "memory");   // drains P1: B(0) in LDS, set0 regs ready
  *(short8*)wA0 = bfadd8(na0, nb0);                   // A(0) -> bufA[0]
  asm volatile("s_waitcnt lgkmcnt(0)" ::: "memory");
  __builtin_amdgcn_s_barrier();

#define CKS(T) do { \
    if ((T) + 2 < 32) CSTB(((T) + 2) * 32, ((T) + 2) % 3); \
    { \
      short8 w = (((T) + 1) & 1) ? bfadd8(na1, nb1) : bfadd8(na0, nb0); \
      *(short8*)(CWA(((T) + 1) % 3)) = w; \
    } \
    if ((T) + 2 < 32) { \
      if (((T) + 2) & 1) { na1 = *(const short8*)(sAc0 + ((T) + 2) * 32); \
                           nb1 = *(const short8*)(sAc1 + ((T) + 2) * 32); } \
      else               { na0 = *(const short8*)(sAc0 + ((T) + 2) * 32); \
                           nb0 = *(const short8*)(sAc1 + ((T) + 2) * 32); } \
    } \
    LDFRAGS(CRA((T) % 3), CRB((T) % 3)); \
    MF16; \
    asm volatile("s_waitcnt lgkmcnt(0)" ::: "memory"); \
    if ((T) < 30)       asm volatile("s_waitcnt vmcnt(4)" ::: "memory"); \
    else if ((T) == 30) asm volatile("s_waitcnt vmcnt(0)" ::: "memory"); \
    if ((T) < 31) __builtin_amdgcn_s_barrier(); \
  } while (0)

  CKS(0);  CKS(1);  CKS(2);  CKS(3);  CKS(4);  CKS(5);  CKS(6);  CKS(7);
  CKS(8);  CKS(9);  CKS(10); CKS(11); CKS(12); CKS(13); CKS(14); CKS(15);
  CKS(16); CKS(17); CKS(18); CKS(19); CKS(20); CKS(21); CKS(22); CKS(23);
  CKS(24); CKS(25); CKS(26); CKS(27); CKS(28); CKS(29); CKS(30); CKS(31);
#undef CKS
#undef CSTB
#undef CDB
#undef CWA
#undef CRA
#undef CRB

  const int colb = ct * 256 + wn * 64 + fr;
#pragma unroll
  for (int m = 0; m < 4; m++)
#pragma unroll
    for (int rr = 0; rr < 4; rr++) {
      int r = rt * 128 + wm * 64 + m * 16 + fq * 4 + rr;
      float* dst = outp + (size_t)r * HID;
#pragma unroll
      for (int n = 0; n < 4; n++) dst[colb + n * 16] = acc[m][n][rr];
    }
}

extern "C" void kernel_launch(void* const* d_in, const int* in_sizes, int n_in,
                              void* d_out, int out_size, void* d_ws, size_t ws_size,
                              hipStream_t stream) {
  const float* tokens    = (const float*)d_in[0];
  const float* gate_w    = (const float*)d_in[1];
  const float* expert_w  = (const float*)d_in[2];
  const float* expert_b  = (const float*)d_in[3];
  const float* combine_w = (const float*)d_in[4];
  float* outp = (float*)d_out;

  char* p = (char*)d_ws;
  ushort* Xb  = (ushort*)p; p += (size_t)NTOK * HID * 2;        // 33.5 MB
  ushort* Wxb = (ushort*)p; p += (size_t)NEXP * HID * HID * 2;  // 16.8 MB
  ushort* Wcb = (ushort*)p; p += (size_t)HID * HID * 2;         //  2.1 MB
  ushort* ctb = (ushort*)p; p += (size_t)2 * NTOK * HID * 2;    // 67.1 MB
  int*   list = (int*)p;    p += (size_t)NEXP * CAP * 4;
  float* lsw  = (float*)p;  p += (size_t)NEXP * CAP * 4;
  int*   cnts = (int*)p;    p += 256;
  uint32_t* tinfo = (uint32_t*)p; p += (size_t)NTOK * 4;
  float2*   twp   = (float2*)p;   p += (size_t)NTOK * 8;

  zero_kernel<<<1, 64, 0, stream>>>(cnts);
  gate_cvt_kernel<<<3328, 256, 0, stream>>>(tokens, gate_w, expert_w, combine_w,
                                            Xb, Wxb, Wcb, tinfo, twp);
  scatter_kernel<<<64, 256, 0, stream>>>(tinfo, twp, list, lsw, cnts);
  egemm_kernel<<<2048, 512, 0, stream>>>(Xb, Wxb, expert_b, list, lsw, cnts, ctb);
  cgemm_kernel<<<512, 512, 0, stream>>>(ctb, Wcb, outp);
}